// Round 1
// baseline (1183.062 us; speedup 1.0000x reference)
//
#include <hip/hip_runtime.h>
#include <hip/hip_bf16.h>

#define N_NODES 100000
#define N_EDGES 1638400
#define IN_CH   128
#define HEADS   4
#define OUT_CH  32
#define HC      (HEADS * OUT_CH)   // 128

// ---------------------------------------------------------------------------
// Kernel 1: h = x @ W^T + b   (fp32, vector ALU — no fp32 MFMA on CDNA4)
// Tile: 64 nodes x 128 cols per block, 256 threads.
// Thread (c = t&31, g = t>>5) computes 8 nodes (g*8..g*8+7) x 4 cols
// {c, c+32, c+64, c+96}  (one col per head — handy layout).
// LDS: W transposed with stride 129 so transpose writes (k*129+o) with k
// consecutive across lanes hit banks (k+o)%32 — conflict-free. Compute reads
// sWt[k*129 + c + 32j] are stride-1 across lanes — conflict-free.
// ---------------------------------------------------------------------------
__launch_bounds__(256)
__global__ void gat_gemm_kernel(const float* __restrict__ x,
                                const float* __restrict__ W,
                                const float* __restrict__ bias,
                                float* __restrict__ h, int n) {
    __shared__ float sWt[128 * 129];     // 66,048 B
    __shared__ float sX[64 * 128];       // 32,768 B   (total ~98 KB < 160 KB)

    const int t = threadIdx.x;
    const int node_base = blockIdx.x * 64;

    // Stage W (global coalesced read, transposed conflict-free LDS write)
    #pragma unroll 4
    for (int i = 0; i < 64; ++i) {
        int idx = i * 256 + t;           // 16384 elements
        int o = idx >> 7, k = idx & 127;
        sWt[k * 129 + o] = W[idx];
    }

    // Stage x tile as float4 (rows are contiguous: 64 rows x 512 B)
    {
        const float4* x4 = (const float4*)(x + (size_t)node_base * IN_CH);
        float4* sX4 = (float4*)sX;
        int rows = n - node_base;        // may be < 64 for last block
        for (int i = t; i < 64 * 32; i += 256) {
            int row = i >> 5;
            float4 v = make_float4(0.f, 0.f, 0.f, 0.f);
            if (row < rows) v = x4[i];
            sX4[i] = v;
        }
    }
    __syncthreads();

    const int c = t & 31;
    const int g = t >> 5;

    float acc[8][4];
    #pragma unroll
    for (int i = 0; i < 8; ++i)
        #pragma unroll
        for (int j = 0; j < 4; ++j) acc[i][j] = 0.f;

    #pragma unroll 4
    for (int k = 0; k < 128; ++k) {
        float w0 = sWt[k * 129 + c];
        float w1 = sWt[k * 129 + c + 32];
        float w2 = sWt[k * 129 + c + 64];
        float w3 = sWt[k * 129 + c + 96];
        #pragma unroll
        for (int i = 0; i < 8; ++i) {
            float xv = sX[(g * 8 + i) * 128 + k];
            acc[i][0] += xv * w0;
            acc[i][1] += xv * w1;
            acc[i][2] += xv * w2;
            acc[i][3] += xv * w3;
        }
    }

    const float b0 = bias[c], b1 = bias[c + 32], b2 = bias[c + 64], b3 = bias[c + 96];
    #pragma unroll
    for (int i = 0; i < 8; ++i) {
        int node = node_base + g * 8 + i;
        if (node < n) {
            float* hp = h + (size_t)node * HC;
            hp[c]      = acc[i][0] + b0;
            hp[c + 32] = acc[i][1] + b1;
            hp[c + 64] = acc[i][2] + b2;
            hp[c + 96] = acc[i][3] + b3;
        }
    }
}

// ---------------------------------------------------------------------------
// Kernel 2: per-node attention scores (reads h L2/L3-warm)
// one thread per (node, head): 32-elem dot with att_l / att_r
// ---------------------------------------------------------------------------
__launch_bounds__(256)
__global__ void gat_alpha_kernel(const float* __restrict__ h,
                                 const float* __restrict__ att_l,
                                 const float* __restrict__ att_r,
                                 float* __restrict__ al,
                                 float* __restrict__ ar, int n) {
    int idx = blockIdx.x * 256 + threadIdx.x;
    if (idx >= n * HEADS) return;
    int node = idx >> 2, head = idx & 3;
    const float4* hp = (const float4*)(h + (size_t)node * HC + head * OUT_CH);
    const float4* lp = (const float4*)(att_l + head * OUT_CH);
    const float4* rp = (const float4*)(att_r + head * OUT_CH);
    float sl = 0.f, sr = 0.f;
    #pragma unroll
    for (int j = 0; j < 8; ++j) {
        float4 v = hp[j], l = lp[j], r = rp[j];
        sl += v.x * l.x + v.y * l.y + v.z * l.z + v.w * l.w;
        sr += v.x * r.x + v.y * r.y + v.z * r.z + v.w * r.w;
    }
    al[idx] = sl;
    ar[idx] = sr;
}

// ---------------------------------------------------------------------------
// Kernel 3: edge gather — the HBM-write-bound hot spot (~865 MB writes)
// 32 lanes per edge; each lane copies one float4 of the 128-float h row.
// Lane 0 computes the 4-head leaky-relu alpha as a single float4.
// ---------------------------------------------------------------------------
__launch_bounds__(256)
__global__ void gat_edge_kernel(const int* __restrict__ src_idx,
                                const int* __restrict__ trg_idx,
                                const float* __restrict__ h,
                                const float* __restrict__ al,
                                const float* __restrict__ ar,
                                float* __restrict__ out_alpha,
                                float* __restrict__ out_x) {
    int tid = blockIdx.x * 256 + threadIdx.x;
    int e = tid >> 5;
    int lane = tid & 31;
    if (e >= N_EDGES) return;

    int src = src_idx[e];

    // x_lifted copy: 512 B per edge, contiguous across lanes & edges
    float4 v = *(const float4*)(h + (size_t)src * HC + lane * 4);
    *(float4*)(out_x + (size_t)e * HC + lane * 4) = v;

    if (lane == 0) {
        int trg = trg_idx[e];
        float4 a = *(const float4*)(al + (size_t)src * HEADS);
        float4 b = *(const float4*)(ar + (size_t)trg * HEADS);
        float4 o;
        float s;
        s = a.x + b.x; o.x = s > 0.f ? s : 0.01f * s;
        s = a.y + b.y; o.y = s > 0.f ? s : 0.01f * s;
        s = a.z + b.z; o.z = s > 0.f ? s : 0.01f * s;
        s = a.w + b.w; o.w = s > 0.f ? s : 0.01f * s;
        *(float4*)(out_alpha + (size_t)e * HEADS) = o;
    }
}

// ---------------------------------------------------------------------------
extern "C" void kernel_launch(void* const* d_in, const int* in_sizes, int n_in,
                              void* d_out, int out_size, void* d_ws, size_t ws_size,
                              hipStream_t stream) {
    const float* x     = (const float*)d_in[0];
    const float* W     = (const float*)d_in[1];
    const float* bias  = (const float*)d_in[2];
    const float* att_l = (const float*)d_in[3];
    const float* att_r = (const float*)d_in[4];
    const int* src_idx = (const int*)d_in[5];
    const int* trg_idx = (const int*)d_in[6];

    // Workspace layout (fp32): h [N,128] | alpha_l [N,4] | alpha_r [N,4]
    float* h  = (float*)d_ws;                                  // 51,200,000 B
    float* al = h + (size_t)N_NODES * HC;                      // +1,600,000 B
    float* ar = al + (size_t)N_NODES * HEADS;                  // +1,600,000 B

    // Outputs: alpha_per_edge [E,4] then x_lifted [E,4,32], concatenated flat
    float* out_alpha = (float*)d_out;
    float* out_x     = out_alpha + (size_t)N_EDGES * HEADS;

    // 1) projection
    int gemm_blocks = (N_NODES + 63) / 64;                     // 1563
    gat_gemm_kernel<<<gemm_blocks, 256, 0, stream>>>(x, W, bias, h, N_NODES);

    // 2) per-node scores
    int alpha_blocks = (N_NODES * HEADS + 255) / 256;          // 1563
    gat_alpha_kernel<<<alpha_blocks, 256, 0, stream>>>(h, att_l, att_r, al, ar, N_NODES);

    // 3) edge gather
    int edge_blocks = (N_EDGES * 32) / 256;                    // 204800
    gat_edge_kernel<<<edge_blocks, 256, 0, stream>>>(src_idx, trg_idx, h, al, ar,
                                                     out_alpha, out_x);
}